// Round 4
// baseline (1449.437 us; speedup 1.0000x reference)
//
#include <hip/hip_runtime.h>

typedef unsigned short u16;
typedef __attribute__((ext_vector_type(8))) short bf16x8;   // 8 bf16 (4 VGPRs)
typedef __attribute__((ext_vector_type(4))) float f32x4;
typedef __attribute__((ext_vector_type(4))) unsigned int uint4v;

#define NLAYER 6
#define D_MODEL 512
#define NHEAD 8
#define DKH 64
#define SEQ 1024
#define BATCH 8
#define FFN 2048
#define MROWS (BATCH * SEQ)  /* 8192 */
#define QKV_LD 1536
#define SCALE_LOG2E 0.18033688011112042f  /* (1/sqrt(64)) * log2(e), folded into Wq/bq */

__device__ __forceinline__ float b2f(u16 u) {
  union { unsigned u32; float f; } x; x.u32 = ((unsigned)u) << 16; return x.f;
}
__device__ __forceinline__ u16 f2b(float f) {
  union { float f; unsigned u; } x; x.f = f;
  unsigned r = x.u + 0x7FFFu + ((x.u >> 16) & 1u);   // RNE
  return (u16)(r >> 16);
}
// async global->LDS, 16B per lane; LDS dest = wave-uniform base + lane*16 (m97)
__device__ __forceinline__ void gld16(const u16* g, u16* l) {
  __builtin_amdgcn_global_load_lds(
      (const __attribute__((address_space(1))) unsigned int*)g,
      (__attribute__((address_space(3))) unsigned int*)l, 16, 0, 0);
}

// ---------- weight transpose + f32->bf16 (xscale folds attn score scale into Wq) ----------
__global__ __launch_bounds__(256) void transpose_cvt_kernel(
    const float* __restrict__ src, u16* __restrict__ dst, int K, int N, size_t dstZ,
    float scale)
{
  __shared__ float t[32][33];
  const int z = blockIdx.z;
  src += (size_t)z * K * N;
  dst += (size_t)z * dstZ;
  const int n0 = blockIdx.x * 32, k0 = blockIdx.y * 32;
  const int tx = threadIdx.x, ty = threadIdx.y;  // 32 x 8
#pragma unroll
  for (int i = 0; i < 32; i += 8)
    t[ty + i][tx] = src[(size_t)(k0 + ty + i) * N + n0 + tx];
  __syncthreads();
#pragma unroll
  for (int i = 0; i < 32; i += 8)
    dst[(size_t)(n0 + ty + i) * K + k0 + tx] = f2b(t[tx][ty + i] * scale);
}

// ---------- concat per-layer q/k/v biases into [L][1536]; bq pre-scaled ----------
__global__ __launch_bounds__(256) void concat_bias_kernel(
    const float* __restrict__ bq, const float* __restrict__ bk,
    const float* __restrict__ bv, float* __restrict__ dst)
{
  const int l = blockIdx.x, t = threadIdx.x;
#pragma unroll
  for (int j = t; j < 512; j += 256) {
    dst[l * QKV_LD + j]        = bq[l * 512 + j] * SCALE_LOG2E;
    dst[l * QKV_LD + 512 + j]  = bk[l * 512 + j];
    dst[l * QKV_LD + 1024 + j] = bv[l * 512 + j];
  }
}

// ---------- embedding: h = emb[ids]*sqrt(D) + pe[s] ----------
__global__ __launch_bounds__(256) void embed_kernel(
    const int* __restrict__ ids, const float* __restrict__ emb,
    const float* __restrict__ pe, float* __restrict__ Hf, u16* __restrict__ Hb)
{
  const int row = blockIdx.x;
  const int s = row & (SEQ - 1);
  const int id = ids[row];
  const int tid = threadIdx.x;
#pragma unroll
  for (int u = 0; u < 2; ++u) {
    const int d = tid + u * 256;
    float v = emb[(size_t)id * D_MODEL + d] * 22.62741699796952f + pe[(size_t)s * D_MODEL + d];
    Hf[(size_t)row * D_MODEL + d] = v;
    Hb[(size_t)row * D_MODEL + d] = f2b(v);
  }
}

// ---------- bf16 MFMA GEMM: C[M,N] = A[M,K] @ Bt[N,K]^T + bias ----------
// BMTx128 tile, BK=32, global_load_lds(16B) staging (m97 pattern).
template<int BMT, bool RELU, bool OUTF, bool OUTB>
__global__ __launch_bounds__(256) void gemm_kernel(
    const u16* __restrict__ A, const u16* __restrict__ Bt,
    const float* __restrict__ bias,
    float* __restrict__ Cf, u16* __restrict__ Cb,
    int M, int N, int K)
{
  constexpr int IT = BMT / 32;                      // 4 (BMT=128) or 2 (BMT=64)
  __shared__ __align__(16) u16 As[BMT * 32];
  __shared__ __align__(16) u16 Bs[128 * 32];
  const int tid = threadIdx.x;
  const int bm = blockIdx.x * BMT, bn = blockIdx.y * 128;
  const int wave = tid >> 6, lane = tid & 63;
  const int lm = lane & 15, quad = lane >> 4;
  const int wm = (wave & 1) * (BMT / 2), wn = (wave >> 1) * 64;
  const int r0 = tid >> 2;            // 0..63
  const int c0 = (tid & 3) * 8;       // 0,8,16,24

  const u16* Ap = A  + (size_t)(bm + r0) * K + c0;
  const u16* Bp = Bt + (size_t)(bn + r0) * K + c0;
  // LDS layout: byte offset == tid*16 for chunk 0 (lane-linear, required by gld)
  u16* lA  = As + wave * 512;
  u16* lA2 = lA + 64 * 32;
  u16* lB  = Bs + wave * 512;
  u16* lB2 = lB + 64 * 32;

  f32x4 acc[IT][4] = {};

  for (int kk = 0; kk < K; kk += 32) {
    __syncthreads();                  // prior iter's frag reads done
    gld16(Ap + kk, lA);
    if (BMT == 128) gld16(Ap + kk + (size_t)64 * K, lA2);
    gld16(Bp + kk, lB);
    gld16(Bp + kk + (size_t)64 * K, lB2);
    __syncthreads();                  // compiler emits vmcnt(0) drain before barrier
    bf16x8 af[IT], bg[4];
#pragma unroll
    for (int i = 0; i < IT; ++i)
      af[i] = *(const bf16x8*)&As[(wm + i * 16 + lm) * 32 + quad * 8];
#pragma unroll
    for (int j = 0; j < 4; ++j)
      bg[j] = *(const bf16x8*)&Bs[(wn + j * 16 + lm) * 32 + quad * 8];
#pragma unroll
    for (int i = 0; i < IT; ++i)
#pragma unroll
      for (int j = 0; j < 4; ++j)
        acc[i][j] = __builtin_amdgcn_mfma_f32_16x16x32_bf16(af[i], bg[j], acc[i][j], 0, 0, 0);
  }

  // epilogue: D row = quad*4+reg, col = lm
  const int mbase = bm + wm + quad * 4;
  const int nbase = bn + wn + lm;
#pragma unroll
  for (int i = 0; i < IT; ++i) {
#pragma unroll
    for (int j = 0; j < 4; ++j) {
      const int n = nbase + j * 16;
      const float bv = bias[n];
#pragma unroll
      for (int r = 0; r < 4; ++r) {
        const int m = mbase + i * 16 + r;
        float v = acc[i][j][r] + bv;
        if (RELU) v = fmaxf(v, 0.f);
        if (OUTF) Cf[(size_t)m * N + n] = v;
        if (OUTB) Cb[(size_t)m * N + n] = f2b(v);
      }
    }
  }
}

// ---------- V^T: qkv[:, 1024+h*64+d] -> vt[bh][d][s] (bf16) ----------
__global__ __launch_bounds__(256) void vt_kernel(
    const u16* __restrict__ QKV, u16* __restrict__ Vt)
{
  __shared__ __align__(16) u16 t[64 * 72];          // stride 72: 144B rows (16B-aligned)
  const int bh = blockIdx.y, s0 = blockIdx.x * 64;
  const int b = bh >> 3, h = bh & 7;
  const int tid = threadIdx.x;
#pragma unroll
  for (int pass = 0; pass < 2; ++pass) {
    const int s = (tid >> 3) + pass * 32, dc = (tid & 7) * 8;
    uint4v w = *(const uint4v*)(QKV + ((size_t)(b * SEQ) + s0 + s) * QKV_LD + 1024 + h * 64 + dc);
    *(uint4v*)&t[s * 72 + dc] = w;
  }
  __syncthreads();
#pragma unroll
  for (int pass = 0; pass < 2; ++pass) {
    const int d = (tid >> 3) + pass * 32, sc = (tid & 7) * 8;
    uint4v o;
#pragma unroll
    for (int q = 0; q < 4; ++q) {
      const unsigned lo = t[(sc + 2 * q) * 72 + d];
      const unsigned hi = t[(sc + 2 * q + 1) * 72 + d];
      o[q] = lo | (hi << 16);
    }
    *(uint4v*)&Vt[((size_t)bh * 64 + d) * SEQ + s0 + sc] = o;
  }
}

// ---------- barrier-free MFMA flash attention, anti-causal mask (keep j > i) ----------
// wave = 16 q-rows; pairs q-units p and 63-p (uniform 17 tile-steps/wave).
// Max-free exp2 softmax (scale folded into Wq/bq); K/V frags register
// double-buffered (prefetch jt+1 during jt); 1-D grid swizzled so all 8 blocks
// of a (b,h) share id%8 -> same XCD under round-robin (K/V stay in that L2).
__global__ __launch_bounds__(256) void attn_mfma_kernel(
    const u16* __restrict__ QKV, const u16* __restrict__ Vt, u16* __restrict__ O)
{
  __shared__ __align__(16) u16 Ps[4 * 16 * 64];
  const int tid = threadIdx.x;
  const int wave = tid >> 6, lane = tid & 63;
  const int quad = lane >> 4, l15 = lane & 15;
  const int id = blockIdx.x;
  const int bh = id & 63;                           // id%8 == h -> XCD affinity
  const int b = bh >> 3, h = bh & 7;
  const int p = (id >> 6) * 4 + wave;               // 0..31
  u16* psw = Ps + wave * (16 * 64);
  const size_t qoff = (size_t)b * SEQ * QKV_LD + h * 64;
  const size_t koff = qoff + 512;
  const size_t vtb  = (size_t)bh * 64 * SEQ;

  for (int half = 0; half < 2; ++half) {
    const int u = half ? (63 - p) : p;              // 16-row q-unit
    const int jt0 = u >> 2;
    const u16* qp = QKV + qoff + (size_t)(u * 16 + l15) * QKV_LD + quad * 8;
    const bf16x8 qf0 = *(const bf16x8*)qp;
    const bf16x8 qf1 = *(const bf16x8*)(qp + 32);

    f32x4 oacc[4] = {};
    float lsum[4] = {0.f, 0.f, 0.f, 0.f};

    bf16x8 ka0[4], ka1[4], va0[4], va1[4];          // ping
    bf16x8 kb0[4], kb1[4], vb0[4], vb1[4];          // pong

    auto loadf = [&](int jt, bf16x8 (&k0)[4], bf16x8 (&k1)[4],
                     bf16x8 (&v0)[4], bf16x8 (&v1)[4]) {
#pragma unroll
      for (int nt = 0; nt < 4; ++nt) {
        const u16* kp = QKV + koff + (size_t)(jt * 64 + nt * 16 + l15) * QKV_LD + quad * 8;
        k0[nt] = *(const bf16x8*)kp;
        k1[nt] = *(const bf16x8*)(kp + 32);
        const u16* vp = Vt + vtb + (size_t)(nt * 16 + l15) * SEQ + jt * 64 + quad * 8;
        v0[nt] = *(const bf16x8*)vp;
        v1[nt] = *(const bf16x8*)(vp + 32);
      }
    };
    auto step = [&](int jt, bool diag, bf16x8 (&k0)[4], bf16x8 (&k1)[4],
                    bf16x8 (&v0)[4], bf16x8 (&v1)[4]) {
      f32x4 sacc[4] = {};
#pragma unroll
      for (int nt = 0; nt < 4; ++nt) {
        sacc[nt] = __builtin_amdgcn_mfma_f32_16x16x32_bf16(qf0, k0[nt], sacc[nt], 0, 0, 0);
        sacc[nt] = __builtin_amdgcn_mfma_f32_16x16x32_bf16(qf1, k1[nt], sacc[nt], 0, 0, 0);
      }
#pragma unroll
      for (int nt = 0; nt < 4; ++nt)
#pragma unroll
        for (int r = 0; r < 4; ++r) {
          float pv = exp2f(sacc[nt][r]);            // scale pre-folded into Q
          if (diag) {                               // wave-uniform branch
            const int i = u * 16 + quad * 4 + r;
            const int j = jt * 64 + nt * 16 + l15;
            pv = (j > i) ? pv : 0.f;                // strictly j > i kept
          }
          lsum[r] += pv;
          const int qr = quad * 4 + r;
          const int j2 = nt * 16 + l15;
          psw[qr * 64 + (((j2 >> 3) ^ (qr & 7)) << 3) + (j2 & 7)] = f2b(pv);
        }
      const int l7 = l15 & 7;
      bf16x8 pf0 = *(const bf16x8*)&psw[l15 * 64 + (((quad + 0) ^ l7) << 3)];
      bf16x8 pf1 = *(const bf16x8*)&psw[l15 * 64 + (((quad + 4) ^ l7) << 3)];
#pragma unroll
      for (int nt = 0; nt < 4; ++nt) {
        oacc[nt] = __builtin_amdgcn_mfma_f32_16x16x32_bf16(pf0, v0[nt], oacc[nt], 0, 0, 0);
        oacc[nt] = __builtin_amdgcn_mfma_f32_16x16x32_bf16(pf1, v1[nt], oacc[nt], 0, 0, 0);
      }
    };

    int jt = jt0;
    loadf(jt, ka0, ka1, va0, va1);
    while (true) {
      if (jt + 1 < 16) loadf(jt + 1, kb0, kb1, vb0, vb1);
      step(jt, jt == jt0, ka0, ka1, va0, va1);
      if (++jt >= 16) break;
      if (jt + 1 < 16) loadf(jt + 1, ka0, ka1, va0, va1);
      step(jt, false, kb0, kb1, vb0, vb1);
      if (++jt >= 16) break;
    }

    // deferred l reduction: sum across the 16 lanes of the quad-row group
#pragma unroll
    for (int o = 1; o < 16; o <<= 1)
#pragma unroll
      for (int r = 0; r < 4; ++r) lsum[r] += __shfl_xor(lsum[r], o, 16);
    float rl[4];
#pragma unroll
    for (int r = 0; r < 4; ++r) rl[r] = 1.0f / lsum[r];   // row 1023: 1/0 -> fixed by vmean
#pragma unroll
    for (int nt = 0; nt < 4; ++nt)
#pragma unroll
      for (int r = 0; r < 4; ++r) {
        const int row = u * 16 + quad * 4 + r;
        O[(size_t)(b * SEQ + row) * D_MODEL + h * DKH + nt * 16 + l15] = f2b(oacc[nt][r] * rl[r]);
      }
  }
}

// ---------- row S-1 fixup: fully-masked row => uniform mean over ALL keys ----------
__global__ __launch_bounds__(256) void vmean_kernel(
    const u16* __restrict__ Vt, u16* __restrict__ O)
{
  const int bh = blockIdx.x, tid = threadIdx.x;
  const int d = tid >> 2, sc = (tid & 3) * 256;
  const u16* p = Vt + ((size_t)bh * 64 + d) * SEQ + sc;
  float s = 0.f;
#pragma unroll 8
  for (int i = 0; i < 256; ++i) s += b2f(p[i]);
  s += __shfl_xor(s, 1, 64);
  s += __shfl_xor(s, 2, 64);
  if ((tid & 3) == 0) {
    const int b = bh >> 3, h = bh & 7;
    O[((size_t)b * SEQ + SEQ - 1) * D_MODEL + h * 64 + d] = f2b(s * (1.f / SEQ));
  }
}

// ---------- fused residual add + LayerNorm; writes f32 (residual) + bf16 (GEMM input) ----------
__global__ __launch_bounds__(256) void add_ln_kernel(
    const float* __restrict__ Hin, const float* __restrict__ T,
    const float* __restrict__ g, const float* __restrict__ bta,
    float* __restrict__ Hout, u16* __restrict__ Hb)
{
  __shared__ float red[8];
  const int row = blockIdx.x, tid = threadIdx.x;
  const int wave = tid >> 6, lane = tid & 63;
  const size_t base = (size_t)row * D_MODEL;
  const float x0 = Hin[base + tid] + T[base + tid];
  const float x1 = Hin[base + tid + 256] + T[base + tid + 256];
  float s = x0 + x1;
#pragma unroll
  for (int o = 32; o > 0; o >>= 1) s += __shfl_xor(s, o, 64);
  if (lane == 0) red[wave] = s;
  __syncthreads();
  const float mu = (red[0] + red[1] + red[2] + red[3]) * (1.f / 512.f);
  const float d0 = x0 - mu, d1 = x1 - mu;
  float v = d0 * d0 + d1 * d1;
#pragma unroll
  for (int o = 32; o > 0; o >>= 1) v += __shfl_xor(v, o, 64);
  if (lane == 0) red[4 + wave] = v;
  __syncthreads();
  const float var = (red[4] + red[5] + red[6] + red[7]) * (1.f / 512.f);
  const float rs = rsqrtf(var + 1e-5f);
  const float y0 = d0 * rs * g[tid] + bta[tid];
  const float y1 = d1 * rs * g[tid + 256] + bta[tid + 256];
  Hout[base + tid] = y0;
  Hout[base + tid + 256] = y1;
  Hb[base + tid] = f2b(y0);
  Hb[base + tid + 256] = f2b(y1);
}

extern "C" void kernel_launch(void* const* d_in, const int* in_sizes, int n_in,
                              void* d_out, int out_size, void* d_ws, size_t ws_size,
                              hipStream_t stream) {
  (void)in_sizes; (void)n_in; (void)out_size; (void)ws_size;
  const int*   ids  = (const int*)  d_in[0];
  const float* emb  = (const float*)d_in[1];
  const float* pe   = (const float*)d_in[2];
  const float* Wq   = (const float*)d_in[3];
  const float* bq   = (const float*)d_in[4];
  const float* Wk   = (const float*)d_in[5];
  const float* bk   = (const float*)d_in[6];
  const float* Wv   = (const float*)d_in[7];
  const float* bv   = (const float*)d_in[8];
  const float* Wo   = (const float*)d_in[9];
  const float* bo   = (const float*)d_in[10];
  const float* g1   = (const float*)d_in[11];
  const float* be1  = (const float*)d_in[12];
  const float* W1   = (const float*)d_in[13];
  const float* b1   = (const float*)d_in[14];
  const float* W2   = (const float*)d_in[15];
  const float* b2   = (const float*)d_in[16];
  const float* g2   = (const float*)d_in[17];
  const float* be2  = (const float*)d_in[18];
  const float* Wout = (const float*)d_in[19];
  const float* bout = (const float*)d_in[20];
  float* out = (float*)d_out;

  char* wsp = (char*)d_ws;
  auto alloc = [&](size_t bytes) -> char* {
    char* p = wsp; wsp += (bytes + 255) & ~(size_t)255; return p;
  };
  const size_t dd  = (size_t)D_MODEL * D_MODEL;      // 262144
  const size_t df  = (size_t)D_MODEL * FFN;          // 1048576
  const size_t dq  = (size_t)QKV_LD * D_MODEL;       // 786432
  u16* wqkv_t = (u16*)alloc(NLAYER * dq * 2);
  u16* wo_t   = (u16*)alloc(NLAYER * dd * 2);
  u16* w1_t   = (u16*)alloc(NLAYER * df * 2);
  u16* w2_t   = (u16*)alloc(NLAYER * df * 2);
  u16* wout_t = (u16*)alloc(dd * 2);
  float* bqkv = (float*)alloc(NLAYER * QKV_LD * 4);
  float* hf   = (float*)alloc((size_t)MROWS * D_MODEL * 4);
  u16*   hb   = (u16*)  alloc((size_t)MROWS * D_MODEL * 2);
  u16*   qkvb = (u16*)  alloc((size_t)MROWS * QKV_LD * 2);   // 24 MB
  u16*   ob   = (u16*)  alloc((size_t)MROWS * D_MODEL * 2);  // 8 MB, right after qkvb
  u16*   vt   = (u16*)  alloc((size_t)BATCH * NHEAD * DKH * SEQ * 2);
  float* tf   = (float*)alloc((size_t)MROWS * D_MODEL * 4);
  u16*   mid  = qkvb;  // FFN mid [8192,2048] aliases qkvb+ob (dead by FFN1; stream-ordered)

  dim3 tb(32, 8);
  transpose_cvt_kernel<<<dim3(16, 16, NLAYER), tb, 0, stream>>>(Wq, wqkv_t,            512, 512,  dq, SCALE_LOG2E);
  transpose_cvt_kernel<<<dim3(16, 16, NLAYER), tb, 0, stream>>>(Wk, wqkv_t + 512*512,  512, 512,  dq, 1.f);
  transpose_cvt_kernel<<<dim3(16, 16, NLAYER), tb, 0, stream>>>(Wv, wqkv_t + 1024*512, 512, 512,  dq, 1.f);
  transpose_cvt_kernel<<<dim3(16, 16, NLAYER), tb, 0, stream>>>(Wo, wo_t,   512, 512,  dd, 1.f);
  transpose_cvt_kernel<<<dim3(64, 16, NLAYER), tb, 0, stream>>>(W1, w1_t,   512, 2048, df, 1.f);
  transpose_cvt_kernel<<<dim3(16, 64, NLAYER), tb, 0, stream>>>(W2, w2_t,   2048, 512, df, 1.f);
  transpose_cvt_kernel<<<dim3(16, 16, 1),      tb, 0, stream>>>(Wout, wout_t, 512, 512, dd, 1.f);
  concat_bias_kernel<<<NLAYER, 256, 0, stream>>>(bq, bk, bv, bqkv);

  embed_kernel<<<MROWS, 256, 0, stream>>>(ids, emb, pe, hf, hb);

  for (int l = 0; l < NLAYER; ++l) {
    gemm_kernel<128, false, false, true><<<dim3(64, 12), 256, 0, stream>>>(
        hb, wqkv_t + l * dq, bqkv + l * QKV_LD, nullptr, qkvb, MROWS, QKV_LD, 512);
    vt_kernel<<<dim3(16, 64), 256, 0, stream>>>(qkvb, vt);
    attn_mfma_kernel<<<512, 256, 0, stream>>>(qkvb, vt, ob);
    vmean_kernel<<<64, 256, 0, stream>>>(vt, ob);
    gemm_kernel<64, false, true, false><<<dim3(128, 4), 256, 0, stream>>>(
        ob, wo_t + l * dd, bo + l * 512, tf, nullptr, MROWS, 512, 512);
    add_ln_kernel<<<MROWS, 256, 0, stream>>>(hf, tf, g1 + l * 512, be1 + l * 512, hf, hb);
    gemm_kernel<128, true, false, true><<<dim3(64, 16), 256, 0, stream>>>(
        hb, w1_t + l * df, b1 + l * 2048, nullptr, mid, MROWS, 2048, 512);
    gemm_kernel<64, false, true, false><<<dim3(128, 4), 256, 0, stream>>>(
        mid, w2_t + l * df, b2 + l * 512, tf, nullptr, MROWS, 512, 2048);
    add_ln_kernel<<<MROWS, 256, 0, stream>>>(hf, tf, g2 + l * 512, be2 + l * 512, hf, hb);
  }
  gemm_kernel<64, false, true, false><<<dim3(128, 4), 256, 0, stream>>>(
      hb, wout_t, bout, out, nullptr, MROWS, 512, 512);
}

// Round 5
// 1424.910 us; speedup vs baseline: 1.0172x; 1.0172x over previous
//
#include <hip/hip_runtime.h>

typedef unsigned short u16;
typedef __attribute__((ext_vector_type(8))) short bf16x8;   // 8 bf16 (4 VGPRs)
typedef __attribute__((ext_vector_type(4))) float f32x4;
typedef __attribute__((ext_vector_type(4))) unsigned int uint4v;

#define NLAYER 6
#define D_MODEL 512
#define NHEAD 8
#define DKH 64
#define SEQ 1024
#define BATCH 8
#define FFN 2048
#define MROWS (BATCH * SEQ)  /* 8192 */
#define QKV_LD 1536
#define SCALE_LOG2E 0.18033688011112042f  /* (1/sqrt(64)) * log2(e), folded into Wq/bq */

__device__ __forceinline__ float b2f(u16 u) {
  union { unsigned u32; float f; } x; x.u32 = ((unsigned)u) << 16; return x.f;
}
__device__ __forceinline__ u16 f2b(float f) {
  union { float f; unsigned u; } x; x.f = f;
  unsigned r = x.u + 0x7FFFu + ((x.u >> 16) & 1u);   // RNE
  return (u16)(r >> 16);
}
// async global->LDS, 16B per lane; LDS dest = wave-uniform base + lane*16 (m97)
__device__ __forceinline__ void gld16(const u16* g, u16* l) {
  __builtin_amdgcn_global_load_lds(
      (const __attribute__((address_space(1))) unsigned int*)g,
      (__attribute__((address_space(3))) unsigned int*)l, 16, 0, 0);
}

// ---------- weight transpose + f32->bf16 (scale folds attn score scale into Wq) ----------
__global__ __launch_bounds__(256) void transpose_cvt_kernel(
    const float* __restrict__ src, u16* __restrict__ dst, int K, int N, size_t dstZ,
    float scale)
{
  __shared__ float t[32][33];
  const int z = blockIdx.z;
  src += (size_t)z * K * N;
  dst += (size_t)z * dstZ;
  const int n0 = blockIdx.x * 32, k0 = blockIdx.y * 32;
  const int tx = threadIdx.x, ty = threadIdx.y;  // 32 x 8
#pragma unroll
  for (int i = 0; i < 32; i += 8)
    t[ty + i][tx] = src[(size_t)(k0 + ty + i) * N + n0 + tx];
  __syncthreads();
#pragma unroll
  for (int i = 0; i < 32; i += 8)
    dst[(size_t)(n0 + ty + i) * K + k0 + tx] = f2b(t[tx][ty + i] * scale);
}

// ---------- concat per-layer q/k/v biases into [L][1536]; bq pre-scaled ----------
__global__ __launch_bounds__(256) void concat_bias_kernel(
    const float* __restrict__ bq, const float* __restrict__ bk,
    const float* __restrict__ bv, float* __restrict__ dst)
{
  const int l = blockIdx.x, t = threadIdx.x;
#pragma unroll
  for (int j = t; j < 512; j += 256) {
    dst[l * QKV_LD + j]        = bq[l * 512 + j] * SCALE_LOG2E;
    dst[l * QKV_LD + 512 + j]  = bk[l * 512 + j];
    dst[l * QKV_LD + 1024 + j] = bv[l * 512 + j];
  }
}

// ---------- embedding: h = emb[ids]*sqrt(D) + pe[s] ----------
__global__ __launch_bounds__(256) void embed_kernel(
    const int* __restrict__ ids, const float* __restrict__ emb,
    const float* __restrict__ pe, float* __restrict__ Hf, u16* __restrict__ Hb)
{
  const int row = blockIdx.x;
  const int s = row & (SEQ - 1);
  const int id = ids[row];
  const int tid = threadIdx.x;
#pragma unroll
  for (int u = 0; u < 2; ++u) {
    const int d = tid + u * 256;
    float v = emb[(size_t)id * D_MODEL + d] * 22.62741699796952f + pe[(size_t)s * D_MODEL + d];
    Hf[(size_t)row * D_MODEL + d] = v;
    Hb[(size_t)row * D_MODEL + d] = f2b(v);
  }
}

// ---------- bf16 MFMA GEMM: C[M,N] = A[M,K] @ Bt[N,K]^T + bias ----------
// BMTx128 tile, BK=32, global_load_lds(16B) staging (m97 pattern).
template<int BMT, bool RELU, bool OUTF, bool OUTB>
__global__ __launch_bounds__(256) void gemm_kernel(
    const u16* __restrict__ A, const u16* __restrict__ Bt,
    const float* __restrict__ bias,
    float* __restrict__ Cf, u16* __restrict__ Cb,
    int M, int N, int K)
{
  constexpr int IT = BMT / 32;                      // 4 (BMT=128) or 2 (BMT=64)
  __shared__ __align__(16) u16 As[BMT * 32];
  __shared__ __align__(16) u16 Bs[128 * 32];
  const int tid = threadIdx.x;
  const int bm = blockIdx.x * BMT, bn = blockIdx.y * 128;
  const int wave = tid >> 6, lane = tid & 63;
  const int lm = lane & 15, quad = lane >> 4;
  const int wm = (wave & 1) * (BMT / 2), wn = (wave >> 1) * 64;
  const int r0 = tid >> 2;            // 0..63
  const int c0 = (tid & 3) * 8;       // 0,8,16,24

  const u16* Ap = A  + (size_t)(bm + r0) * K + c0;
  const u16* Bp = Bt + (size_t)(bn + r0) * K + c0;
  // LDS layout: byte offset == tid*16 for chunk 0 (lane-linear, required by gld)
  u16* lA  = As + wave * 512;
  u16* lA2 = lA + 64 * 32;
  u16* lB  = Bs + wave * 512;
  u16* lB2 = lB + 64 * 32;

  f32x4 acc[IT][4] = {};

  for (int kk = 0; kk < K; kk += 32) {
    __syncthreads();                  // prior iter's frag reads done
    gld16(Ap + kk, lA);
    if (BMT == 128) gld16(Ap + kk + (size_t)64 * K, lA2);
    gld16(Bp + kk, lB);
    gld16(Bp + kk + (size_t)64 * K, lB2);
    __syncthreads();                  // compiler emits vmcnt(0) drain before barrier
    bf16x8 af[IT], bg[4];
#pragma unroll
    for (int i = 0; i < IT; ++i)
      af[i] = *(const bf16x8*)&As[(wm + i * 16 + lm) * 32 + quad * 8];
#pragma unroll
    for (int j = 0; j < 4; ++j)
      bg[j] = *(const bf16x8*)&Bs[(wn + j * 16 + lm) * 32 + quad * 8];
#pragma unroll
    for (int i = 0; i < IT; ++i)
#pragma unroll
      for (int j = 0; j < 4; ++j)
        acc[i][j] = __builtin_amdgcn_mfma_f32_16x16x32_bf16(af[i], bg[j], acc[i][j], 0, 0, 0);
  }

  // epilogue: D row = quad*4+reg, col = lm
  const int mbase = bm + wm + quad * 4;
  const int nbase = bn + wn + lm;
#pragma unroll
  for (int i = 0; i < IT; ++i) {
#pragma unroll
    for (int j = 0; j < 4; ++j) {
      const int n = nbase + j * 16;
      const float bv = bias[n];
#pragma unroll
      for (int r = 0; r < 4; ++r) {
        const int m = mbase + i * 16 + r;
        float v = acc[i][j][r] + bv;
        if (RELU) v = fmaxf(v, 0.f);
        if (OUTF) Cf[(size_t)m * N + n] = v;
        if (OUTB) Cb[(size_t)m * N + n] = f2b(v);
      }
    }
  }
}

// ---------- V^T: qkv[:, 1024+h*64+d] -> vt[bh][d][s] (bf16) ----------
__global__ __launch_bounds__(256) void vt_kernel(
    const u16* __restrict__ QKV, u16* __restrict__ Vt)
{
  __shared__ __align__(16) u16 t[64 * 72];          // stride 72: 144B rows (16B-aligned)
  const int bh = blockIdx.y, s0 = blockIdx.x * 64;
  const int b = bh >> 3, h = bh & 7;
  const int tid = threadIdx.x;
#pragma unroll
  for (int pass = 0; pass < 2; ++pass) {
    const int s = (tid >> 3) + pass * 32, dc = (tid & 7) * 8;
    uint4v w = *(const uint4v*)(QKV + ((size_t)(b * SEQ) + s0 + s) * QKV_LD + 1024 + h * 64 + dc);
    *(uint4v*)&t[s * 72 + dc] = w;
  }
  __syncthreads();
#pragma unroll
  for (int pass = 0; pass < 2; ++pass) {
    const int d = (tid >> 3) + pass * 32, sc = (tid & 7) * 8;
    uint4v o;
#pragma unroll
    for (int q = 0; q < 4; ++q) {
      const unsigned lo = t[(sc + 2 * q) * 72 + d];
      const unsigned hi = t[(sc + 2 * q + 1) * 72 + d];
      o[q] = lo | (hi << 16);
    }
    *(uint4v*)&Vt[((size_t)bh * 64 + d) * SEQ + s0 + sc] = o;
  }
}

// ---------- barrier-free MFMA flash attention, anti-causal mask (keep j > i) ----------
// wave = 16 q-rows; pairs q-units p and 63-p (uniform 17 tile-steps/wave).
// Max-free exp2 softmax (scale folded into Wq/bq). Register budget discipline:
// ONE K buffer + ONE V buffer (32 VGPR each), sequenced so each load batch's
// latency is covered: QK(jt) -> issue V(jt) -> issue K(jt+1) -> softmax -> PV(jt).
// 1-D grid: id&63 = bh, so all 8 blocks of a (b,h) share id%8 -> same XCD.
__global__ __launch_bounds__(256) void attn_mfma_kernel(
    const u16* __restrict__ QKV, const u16* __restrict__ Vt, u16* __restrict__ O)
{
  __shared__ __align__(16) u16 Ps[4 * 16 * 64];
  const int tid = threadIdx.x;
  const int wave = tid >> 6, lane = tid & 63;
  const int quad = lane >> 4, l15 = lane & 15;
  const int l7 = l15 & 7;
  const int id = blockIdx.x;
  const int bh = id & 63;                           // id%8 == h -> XCD affinity
  const int b = bh >> 3, h = bh & 7;
  const int p = (id >> 6) * 4 + wave;               // 0..31
  u16* psw = Ps + wave * (16 * 64);
  const size_t qoff = (size_t)b * SEQ * QKV_LD + h * 64;
  const size_t vtb  = (size_t)bh * 64 * SEQ;
  // K lane base: row nt*16+l15, col quad*8 (within this head's K block)
  const u16* kbase = QKV + qoff + 512 + (size_t)l15 * QKV_LD + quad * 8;
  const u16* vbase = Vt + vtb + (size_t)l15 * SEQ + quad * 8;

  for (int half = 0; half < 2; ++half) {
    const int u = half ? (63 - p) : p;              // 16-row q-unit
    const int jt0 = u >> 2;
    const u16* qp = QKV + qoff + (size_t)(u * 16 + l15) * QKV_LD + quad * 8;
    const bf16x8 qf0 = *(const bf16x8*)qp;
    const bf16x8 qf1 = *(const bf16x8*)(qp + 32);

    f32x4 oacc[4] = {};
    float lsum[4] = {0.f, 0.f, 0.f, 0.f};

    bf16x8 kf0[4], kf1[4], vf0[4], vf1[4];
    // prime K(jt0): 8 b128 loads, batched
#pragma unroll
    for (int nt = 0; nt < 4; ++nt) {
      const u16* kp = kbase + (size_t)(jt0 * 64 + nt * 16) * QKV_LD;
      kf0[nt] = *(const bf16x8*)kp;
      kf1[nt] = *(const bf16x8*)(kp + 32);
    }

#pragma unroll 1
    for (int jt = jt0; jt < 16; ++jt) {
      // QK: consumes kf (regs free for next-tile loads after issue)
      f32x4 sacc[4] = {};
#pragma unroll
      for (int nt = 0; nt < 4; ++nt) {
        sacc[nt] = __builtin_amdgcn_mfma_f32_16x16x32_bf16(qf0, kf0[nt], sacc[nt], 0, 0, 0);
        sacc[nt] = __builtin_amdgcn_mfma_f32_16x16x32_bf16(qf1, kf1[nt], sacc[nt], 0, 0, 0);
      }
      // issue V(jt) batch — latency covered by softmax below
#pragma unroll
      for (int nt = 0; nt < 4; ++nt) {
        const u16* vp = vbase + (size_t)(nt * 16) * SEQ + jt * 64;
        vf0[nt] = *(const bf16x8*)vp;
        vf1[nt] = *(const bf16x8*)(vp + 32);
      }
      // issue K(jt+1) batch into the (now free) K regs — covered by softmax+PV
      if (jt < 15) {
#pragma unroll
        for (int nt = 0; nt < 4; ++nt) {
          const u16* kp = kbase + (size_t)((jt + 1) * 64 + nt * 16) * QKV_LD;
          kf0[nt] = *(const bf16x8*)kp;
          kf1[nt] = *(const bf16x8*)(kp + 32);
        }
      }
      // max-free softmax (scale pre-folded into Q): p = exp2(s), mask on diag tile
      const bool diag = (jt == jt0);
#pragma unroll
      for (int nt = 0; nt < 4; ++nt)
#pragma unroll
        for (int r = 0; r < 4; ++r) {
          float pv = __builtin_amdgcn_exp2f(sacc[nt][r]);
          if (diag) {
            const int i = u * 16 + quad * 4 + r;
            const int j = jt * 64 + nt * 16 + l15;
            pv = (j > i) ? pv : 0.f;                // keep strictly j > i
          }
          lsum[r] += pv;
          const int qr = quad * 4 + r;
          const int j2 = nt * 16 + l15;
          psw[qr * 64 + (((j2 >> 3) ^ (qr & 7)) << 3) + (j2 & 7)] = f2b(pv);
        }
      // P frags from per-wave LDS (same-wave RAW, no barrier)
      bf16x8 pf0 = *(const bf16x8*)&psw[l15 * 64 + (((quad + 0) ^ l7) << 3)];
      bf16x8 pf1 = *(const bf16x8*)&psw[l15 * 64 + (((quad + 4) ^ l7) << 3)];
      // PV: waits only on V batch (K(jt+1) may still be in flight)
#pragma unroll
      for (int nt = 0; nt < 4; ++nt) {
        oacc[nt] = __builtin_amdgcn_mfma_f32_16x16x32_bf16(pf0, vf0[nt], oacc[nt], 0, 0, 0);
        oacc[nt] = __builtin_amdgcn_mfma_f32_16x16x32_bf16(pf1, vf1[nt], oacc[nt], 0, 0, 0);
      }
    }

    // deferred l reduction across the 16 lanes of the quad-row group
#pragma unroll
    for (int o = 1; o < 16; o <<= 1)
#pragma unroll
      for (int r = 0; r < 4; ++r) lsum[r] += __shfl_xor(lsum[r], o, 16);
    float rl[4];
#pragma unroll
    for (int r = 0; r < 4; ++r) rl[r] = 1.0f / lsum[r];   // row 1023: fixed by vmean
#pragma unroll
    for (int nt = 0; nt < 4; ++nt)
#pragma unroll
      for (int r = 0; r < 4; ++r) {
        const int row = u * 16 + quad * 4 + r;
        O[(size_t)(b * SEQ + row) * D_MODEL + h * DKH + nt * 16 + l15] = f2b(oacc[nt][r] * rl[r]);
      }
  }
}

// ---------- row S-1 fixup: fully-masked row => uniform mean over ALL keys ----------
__global__ __launch_bounds__(256) void vmean_kernel(
    const u16* __restrict__ Vt, u16* __restrict__ O)
{
  const int bh = blockIdx.x, tid = threadIdx.x;
  const int d = tid >> 2, sc = (tid & 3) * 256;
  const u16* p = Vt + ((size_t)bh * 64 + d) * SEQ + sc;
  float s = 0.f;
#pragma unroll 8
  for (int i = 0; i < 256; ++i) s += b2f(p[i]);
  s += __shfl_xor(s, 1, 64);
  s += __shfl_xor(s, 2, 64);
  if ((tid & 3) == 0) {
    const int b = bh >> 3, h = bh & 7;
    O[((size_t)b * SEQ + SEQ - 1) * D_MODEL + h * 64 + d] = f2b(s * (1.f / SEQ));
  }
}

// ---------- fused residual add + LayerNorm; writes f32 (residual) + bf16 (GEMM input) ----------
__global__ __launch_bounds__(256) void add_ln_kernel(
    const float* __restrict__ Hin, const float* __restrict__ T,
    const float* __restrict__ g, const float* __restrict__ bta,
    float* __restrict__ Hout, u16* __restrict__ Hb)
{
  __shared__ float red[8];
  const int row = blockIdx.x, tid = threadIdx.x;
  const int wave = tid >> 6, lane = tid & 63;
  const size_t base = (size_t)row * D_MODEL;
  const float x0 = Hin[base + tid] + T[base + tid];
  const float x1 = Hin[base + tid + 256] + T[base + tid + 256];
  float s = x0 + x1;
#pragma unroll
  for (int o = 32; o > 0; o >>= 1) s += __shfl_xor(s, o, 64);
  if (lane == 0) red[wave] = s;
  __syncthreads();
  const float mu = (red[0] + red[1] + red[2] + red[3]) * (1.f / 512.f);
  const float d0 = x0 - mu, d1 = x1 - mu;
  float v = d0 * d0 + d1 * d1;
#pragma unroll
  for (int o = 32; o > 0; o >>= 1) v += __shfl_xor(v, o, 64);
  if (lane == 0) red[4 + wave] = v;
  __syncthreads();
  const float var = (red[4] + red[5] + red[6] + red[7]) * (1.f / 512.f);
  const float rs = rsqrtf(var + 1e-5f);
  const float y0 = d0 * rs * g[tid] + bta[tid];
  const float y1 = d1 * rs * g[tid + 256] + bta[tid + 256];
  Hout[base + tid] = y0;
  Hout[base + tid + 256] = y1;
  Hb[base + tid] = f2b(y0);
  Hb[base + tid + 256] = f2b(y1);
}

extern "C" void kernel_launch(void* const* d_in, const int* in_sizes, int n_in,
                              void* d_out, int out_size, void* d_ws, size_t ws_size,
                              hipStream_t stream) {
  (void)in_sizes; (void)n_in; (void)out_size; (void)ws_size;
  const int*   ids  = (const int*)  d_in[0];
  const float* emb  = (const float*)d_in[1];
  const float* pe   = (const float*)d_in[2];
  const float* Wq   = (const float*)d_in[3];
  const float* bq   = (const float*)d_in[4];
  const float* Wk   = (const float*)d_in[5];
  const float* bk   = (const float*)d_in[6];
  const float* Wv   = (const float*)d_in[7];
  const float* bv   = (const float*)d_in[8];
  const float* Wo   = (const float*)d_in[9];
  const float* bo   = (const float*)d_in[10];
  const float* g1   = (const float*)d_in[11];
  const float* be1  = (const float*)d_in[12];
  const float* W1   = (const float*)d_in[13];
  const float* b1   = (const float*)d_in[14];
  const float* W2   = (const float*)d_in[15];
  const float* b2   = (const float*)d_in[16];
  const float* g2   = (const float*)d_in[17];
  const float* be2  = (const float*)d_in[18];
  const float* Wout = (const float*)d_in[19];
  const float* bout = (const float*)d_in[20];
  float* out = (float*)d_out;

  char* wsp = (char*)d_ws;
  auto alloc = [&](size_t bytes) -> char* {
    char* p = wsp; wsp += (bytes + 255) & ~(size_t)255; return p;
  };
  const size_t dd  = (size_t)D_MODEL * D_MODEL;      // 262144
  const size_t df  = (size_t)D_MODEL * FFN;          // 1048576
  const size_t dq  = (size_t)QKV_LD * D_MODEL;       // 786432
  u16* wqkv_t = (u16*)alloc(NLAYER * dq * 2);
  u16* wo_t   = (u16*)alloc(NLAYER * dd * 2);
  u16* w1_t   = (u16*)alloc(NLAYER * df * 2);
  u16* w2_t   = (u16*)alloc(NLAYER * df * 2);
  u16* wout_t = (u16*)alloc(dd * 2);
  float* bqkv = (float*)alloc(NLAYER * QKV_LD * 4);
  float* hf   = (float*)alloc((size_t)MROWS * D_MODEL * 4);
  u16*   hb   = (u16*)  alloc((size_t)MROWS * D_MODEL * 2);
  u16*   qkvb = (u16*)  alloc((size_t)MROWS * QKV_LD * 2);   // 24 MB
  u16*   ob   = (u16*)  alloc((size_t)MROWS * D_MODEL * 2);  // 8 MB
  u16*   vt   = (u16*)  alloc((size_t)BATCH * NHEAD * DKH * SEQ * 2);
  float* tf   = (float*)alloc((size_t)MROWS * D_MODEL * 4);
  u16*   mid  = qkvb;  // FFN mid [8192,2048] aliases qkvb+ob (dead by FFN1; stream-ordered)

  dim3 tb(32, 8);
  transpose_cvt_kernel<<<dim3(16, 16, NLAYER), tb, 0, stream>>>(Wq, wqkv_t,            512, 512,  dq, SCALE_LOG2E);
  transpose_cvt_kernel<<<dim3(16, 16, NLAYER), tb, 0, stream>>>(Wk, wqkv_t + 512*512,  512, 512,  dq, 1.f);
  transpose_cvt_kernel<<<dim3(16, 16, NLAYER), tb, 0, stream>>>(Wv, wqkv_t + 1024*512, 512, 512,  dq, 1.f);
  transpose_cvt_kernel<<<dim3(16, 16, NLAYER), tb, 0, stream>>>(Wo, wo_t,   512, 512,  dd, 1.f);
  transpose_cvt_kernel<<<dim3(64, 16, NLAYER), tb, 0, stream>>>(W1, w1_t,   512, 2048, df, 1.f);
  transpose_cvt_kernel<<<dim3(16, 64, NLAYER), tb, 0, stream>>>(W2, w2_t,   2048, 512, df, 1.f);
  transpose_cvt_kernel<<<dim3(16, 16, 1),      tb, 0, stream>>>(Wout, wout_t, 512, 512, dd, 1.f);
  concat_bias_kernel<<<NLAYER, 256, 0, stream>>>(bq, bk, bv, bqkv);

  embed_kernel<<<MROWS, 256, 0, stream>>>(ids, emb, pe, hf, hb);

  for (int l = 0; l < NLAYER; ++l) {
    gemm_kernel<128, false, false, true><<<dim3(64, 12), 256, 0, stream>>>(
        hb, wqkv_t + l * dq, bqkv + l * QKV_LD, nullptr, qkvb, MROWS, QKV_LD, 512);
    vt_kernel<<<dim3(16, 64), 256, 0, stream>>>(qkvb, vt);
    attn_mfma_kernel<<<512, 256, 0, stream>>>(qkvb, vt, ob);
    vmean_kernel<<<64, 256, 0, stream>>>(vt, ob);
    gemm_kernel<64, false, true, false><<<dim3(128, 4), 256, 0, stream>>>(
        ob, wo_t + l * dd, bo + l * 512, tf, nullptr, MROWS, 512, 512);
    add_ln_kernel<<<MROWS, 256, 0, stream>>>(hf, tf, g1 + l * 512, be1 + l * 512, hf, hb);
    gemm_kernel<128, true, false, true><<<dim3(64, 16), 256, 0, stream>>>(
        hb, w1_t + l * df, b1 + l * 2048, nullptr, mid, MROWS, 2048, 512);
    gemm_kernel<64, false, true, false><<<dim3(128, 4), 256, 0, stream>>>(
        mid, w2_t + l * df, b2 + l * 512, tf, nullptr, MROWS, 512, 2048);
    add_ln_kernel<<<MROWS, 256, 0, stream>>>(hf, tf, g2 + l * 512, be2 + l * 512, hf, hb);
  }
  gemm_kernel<64, false, true, false><<<dim3(128, 4), 256, 0, stream>>>(
      hb, wout_t, bout, out, nullptr, MROWS, 512, 512);
}

// Round 6
// 1409.459 us; speedup vs baseline: 1.0284x; 1.0110x over previous
//
#include <hip/hip_runtime.h>

typedef unsigned short u16;
typedef __attribute__((ext_vector_type(8))) short bf16x8;   // 8 bf16 (4 VGPRs)
typedef __attribute__((ext_vector_type(4))) float f32x4;
typedef __attribute__((ext_vector_type(4))) unsigned int uint4v;
typedef __attribute__((ext_vector_type(4))) unsigned short us4;

#define NLAYER 6
#define D_MODEL 512
#define NHEAD 8
#define DKH 64
#define SEQ 1024
#define BATCH 8
#define FFN 2048
#define MROWS (BATCH * SEQ)  /* 8192 */
#define QKV_LD 1536
#define SCALE_LOG2E 0.18033688011112042f  /* (1/sqrt(64)) * log2(e), folded into Wq/bq */

__device__ __forceinline__ float b2f(u16 u) {
  union { unsigned u32; float f; } x; x.u32 = ((unsigned)u) << 16; return x.f;
}
__device__ __forceinline__ u16 f2b(float f) {
  union { float f; unsigned u; } x; x.f = f;
  unsigned r = x.u + 0x7FFFu + ((x.u >> 16) & 1u);   // RNE
  return (u16)(r >> 16);
}
// async global->LDS, 16B per lane; LDS dest = wave-uniform base + lane*16 (m97)
__device__ __forceinline__ void gld16(const u16* g, u16* l) {
  __builtin_amdgcn_global_load_lds(
      (const __attribute__((address_space(1))) unsigned int*)g,
      (__attribute__((address_space(3))) unsigned int*)l, 16, 0, 0);
}

// ---------- weight transpose + f32->bf16 (scale folds attn score scale into Wq) ----------
__global__ __launch_bounds__(256) void transpose_cvt_kernel(
    const float* __restrict__ src, u16* __restrict__ dst, int K, int N, size_t dstZ,
    float scale)
{
  __shared__ float t[32][33];
  const int z = blockIdx.z;
  src += (size_t)z * K * N;
  dst += (size_t)z * dstZ;
  const int n0 = blockIdx.x * 32, k0 = blockIdx.y * 32;
  const int tx = threadIdx.x, ty = threadIdx.y;  // 32 x 8
#pragma unroll
  for (int i = 0; i < 32; i += 8)
    t[ty + i][tx] = src[(size_t)(k0 + ty + i) * N + n0 + tx];
  __syncthreads();
#pragma unroll
  for (int i = 0; i < 32; i += 8)
    dst[(size_t)(n0 + ty + i) * K + k0 + tx] = f2b(t[tx][ty + i] * scale);
}

// ---------- concat per-layer q/k/v biases into [L][1536]; bq pre-scaled ----------
__global__ __launch_bounds__(256) void concat_bias_kernel(
    const float* __restrict__ bq, const float* __restrict__ bk,
    const float* __restrict__ bv, float* __restrict__ dst)
{
  const int l = blockIdx.x, t = threadIdx.x;
#pragma unroll
  for (int j = t; j < 512; j += 256) {
    dst[l * QKV_LD + j]        = bq[l * 512 + j] * SCALE_LOG2E;
    dst[l * QKV_LD + 512 + j]  = bk[l * 512 + j];
    dst[l * QKV_LD + 1024 + j] = bv[l * 512 + j];
  }
}

// ---------- embedding: h = emb[ids]*sqrt(D) + pe[s] ----------
__global__ __launch_bounds__(256) void embed_kernel(
    const int* __restrict__ ids, const float* __restrict__ emb,
    const float* __restrict__ pe, float* __restrict__ Hf, u16* __restrict__ Hb)
{
  const int row = blockIdx.x;
  const int s = row & (SEQ - 1);
  const int id = ids[row];
  const int tid = threadIdx.x;
#pragma unroll
  for (int u = 0; u < 2; ++u) {
    const int d = tid + u * 256;
    float v = emb[(size_t)id * D_MODEL + d] * 22.62741699796952f + pe[(size_t)s * D_MODEL + d];
    Hf[(size_t)row * D_MODEL + d] = v;
    Hb[(size_t)row * D_MODEL + d] = f2b(v);
  }
}

// ---------- bf16 MFMA GEMM: C[M,N] = A[M,K] @ Bt[N,K]^T + bias ----------
// BMTx128 tile, BK=32, global_load_lds(16B) staging (m97 pattern).
// VT mode (QKV GEMM): columns n>=1024 (the V projection) are written
// TRANSPOSED into Vt[bh][d][s] as packed 4x bf16 (8B) stores; their qkvb
// copy is skipped (attention reads V only via Vt).
template<int BMT, bool RELU, bool OUTF, bool OUTB, bool VT>
__global__ __launch_bounds__(256) void gemm_kernel(
    const u16* __restrict__ A, const u16* __restrict__ Bt,
    const float* __restrict__ bias,
    float* __restrict__ Cf, u16* __restrict__ Cb, u16* __restrict__ Vtp,
    int M, int N, int K)
{
  constexpr int IT = BMT / 32;                      // 4 (BMT=128) or 2 (BMT=64)
  __shared__ __align__(16) u16 As[BMT * 32];
  __shared__ __align__(16) u16 Bs[128 * 32];
  const int tid = threadIdx.x;
  const int bm = blockIdx.x * BMT, bn = blockIdx.y * 128;
  const int wave = tid >> 6, lane = tid & 63;
  const int lm = lane & 15, quad = lane >> 4;
  const int wm = (wave & 1) * (BMT / 2), wn = (wave >> 1) * 64;
  const int r0 = tid >> 2;            // 0..63
  const int c0 = (tid & 3) * 8;       // 0,8,16,24

  const u16* Ap = A  + (size_t)(bm + r0) * K + c0;
  const u16* Bp = Bt + (size_t)(bn + r0) * K + c0;
  // LDS layout: byte offset == tid*16 for chunk 0 (lane-linear, required by gld)
  u16* lA  = As + wave * 512;
  u16* lA2 = lA + 64 * 32;
  u16* lB  = Bs + wave * 512;
  u16* lB2 = lB + 64 * 32;

  f32x4 acc[IT][4] = {};

  for (int kk = 0; kk < K; kk += 32) {
    __syncthreads();                  // prior iter's frag reads done
    gld16(Ap + kk, lA);
    if (BMT == 128) gld16(Ap + kk + (size_t)64 * K, lA2);
    gld16(Bp + kk, lB);
    gld16(Bp + kk + (size_t)64 * K, lB2);
    __syncthreads();                  // compiler emits vmcnt(0) drain before barrier
    bf16x8 af[IT], bg[4];
#pragma unroll
    for (int i = 0; i < IT; ++i)
      af[i] = *(const bf16x8*)&As[(wm + i * 16 + lm) * 32 + quad * 8];
#pragma unroll
    for (int j = 0; j < 4; ++j)
      bg[j] = *(const bf16x8*)&Bs[(wn + j * 16 + lm) * 32 + quad * 8];
#pragma unroll
    for (int i = 0; i < IT; ++i)
#pragma unroll
      for (int j = 0; j < 4; ++j)
        acc[i][j] = __builtin_amdgcn_mfma_f32_16x16x32_bf16(af[i], bg[j], acc[i][j], 0, 0, 0);
  }

  // epilogue: D row = quad*4+reg, col = lm
  const int mbase = bm + wm + quad * 4;
  const int nbase = bn + wn + lm;
#pragma unroll
  for (int i = 0; i < IT; ++i) {
#pragma unroll
    for (int j = 0; j < 4; ++j) {
      const int n = nbase + j * 16;
      const float bv = bias[n];
      float vv[4];
#pragma unroll
      for (int r = 0; r < 4; ++r) {
        float v = acc[i][j][r] + bv;
        if (RELU) v = fmaxf(v, 0.f);
        vv[r] = v;
      }
      if (VT && n >= 1024) {
        // V column: write transposed, 4 consecutive s per lane (8B store)
        const int hh = (n - 1024) >> 6, d = (n - 1024) & 63;
        const int mm = mbase + i * 16;               // mm..mm+3, 4-aligned
        const int bb = mm >> 10, ss = mm & 1023;
        us4 pk;
#pragma unroll
        for (int r = 0; r < 4; ++r) pk[r] = f2b(vv[r]);
        *(us4*)&Vtp[(((size_t)(bb * NHEAD + hh)) * 64 + d) * SEQ + ss] = pk;
      } else {
#pragma unroll
        for (int r = 0; r < 4; ++r) {
          const int m = mbase + i * 16 + r;
          if (OUTF) Cf[(size_t)m * N + n] = vv[r];
          if (OUTB) Cb[(size_t)m * N + n] = f2b(vv[r]);
        }
      }
    }
  }
}

// ---------- barrier-free MFMA flash attention, anti-causal mask (keep j > i) ----------
// ONE 16-row q-unit per wave (u = (id>>6)*4+wave); 1024 blocks -> 4 blocks/CU,
// 16 waves/CU for TLP latency hiding. Max-free exp2 softmax (scale folded into
// Wq/bq); one K + one V register buffer, load batches covered by softmax/PV.
// 1-D grid: id&63 = bh, so all 16 blocks of a (b,h) share id%8 -> same XCD.
__global__ __launch_bounds__(256) void attn_mfma_kernel(
    const u16* __restrict__ QKV, const u16* __restrict__ Vt, u16* __restrict__ O)
{
  __shared__ __align__(16) u16 Ps[4 * 16 * 64];
  const int tid = threadIdx.x;
  const int wave = tid >> 6, lane = tid & 63;
  const int quad = lane >> 4, l15 = lane & 15;
  const int l7 = l15 & 7;
  const int id = blockIdx.x;
  const int bh = id & 63;                           // id%8 == h -> XCD affinity
  const int b = bh >> 3, h = bh & 7;
  const int u = (id >> 6) * 4 + wave;               // q-unit 0..63
  const int jt0 = u >> 2;
  u16* psw = Ps + wave * (16 * 64);
  const size_t qoff = (size_t)b * SEQ * QKV_LD + h * 64;
  const size_t vtb  = (size_t)bh * 64 * SEQ;
  const u16* kbase = QKV + qoff + 512 + (size_t)l15 * QKV_LD + quad * 8;
  const u16* vbase = Vt + vtb + (size_t)l15 * SEQ + quad * 8;

  const u16* qp = QKV + qoff + (size_t)(u * 16 + l15) * QKV_LD + quad * 8;
  const bf16x8 qf0 = *(const bf16x8*)qp;
  const bf16x8 qf1 = *(const bf16x8*)(qp + 32);

  f32x4 oacc[4] = {};
  float lsum[4] = {0.f, 0.f, 0.f, 0.f};

  bf16x8 kf0[4], kf1[4], vf0[4], vf1[4];
  // prime K(jt0): 8 b128 loads, batched
#pragma unroll
  for (int nt = 0; nt < 4; ++nt) {
    const u16* kp = kbase + (size_t)(jt0 * 64 + nt * 16) * QKV_LD;
    kf0[nt] = *(const bf16x8*)kp;
    kf1[nt] = *(const bf16x8*)(kp + 32);
  }

#pragma unroll 1
  for (int jt = jt0; jt < 16; ++jt) {
    // QK: consumes kf (regs free for next-tile loads after issue)
    f32x4 sacc[4] = {};
#pragma unroll
    for (int nt = 0; nt < 4; ++nt) {
      sacc[nt] = __builtin_amdgcn_mfma_f32_16x16x32_bf16(qf0, kf0[nt], sacc[nt], 0, 0, 0);
      sacc[nt] = __builtin_amdgcn_mfma_f32_16x16x32_bf16(qf1, kf1[nt], sacc[nt], 0, 0, 0);
    }
    // issue V(jt) batch — latency covered by softmax below
#pragma unroll
    for (int nt = 0; nt < 4; ++nt) {
      const u16* vp = vbase + (size_t)(nt * 16) * SEQ + jt * 64;
      vf0[nt] = *(const bf16x8*)vp;
      vf1[nt] = *(const bf16x8*)(vp + 32);
    }
    // issue K(jt+1) batch into the (now free) K regs — covered by softmax+PV
    if (jt < 15) {
#pragma unroll
      for (int nt = 0; nt < 4; ++nt) {
        const u16* kp = kbase + (size_t)((jt + 1) * 64 + nt * 16) * QKV_LD;
        kf0[nt] = *(const bf16x8*)kp;
        kf1[nt] = *(const bf16x8*)(kp + 32);
      }
    }
    // max-free softmax (scale pre-folded into Q): p = exp2(s), mask on diag tile
    const bool diag = (jt == jt0);
#pragma unroll
    for (int nt = 0; nt < 4; ++nt)
#pragma unroll
      for (int r = 0; r < 4; ++r) {
        float pv = __builtin_amdgcn_exp2f(sacc[nt][r]);
        if (diag) {
          const int i = u * 16 + quad * 4 + r;
          const int j = jt * 64 + nt * 16 + l15;
          pv = (j > i) ? pv : 0.f;                  // keep strictly j > i
        }
        lsum[r] += pv;
        const int qr = quad * 4 + r;
        const int j2 = nt * 16 + l15;
        psw[qr * 64 + (((j2 >> 3) ^ (qr & 7)) << 3) + (j2 & 7)] = f2b(pv);
      }
    // P frags from per-wave LDS (same-wave RAW, no barrier)
    bf16x8 pf0 = *(const bf16x8*)&psw[l15 * 64 + (((quad + 0) ^ l7) << 3)];
    bf16x8 pf1 = *(const bf16x8*)&psw[l15 * 64 + (((quad + 4) ^ l7) << 3)];
    // PV: waits only on V batch (K(jt+1) may still be in flight)
#pragma unroll
    for (int nt = 0; nt < 4; ++nt) {
      oacc[nt] = __builtin_amdgcn_mfma_f32_16x16x32_bf16(pf0, vf0[nt], oacc[nt], 0, 0, 0);
      oacc[nt] = __builtin_amdgcn_mfma_f32_16x16x32_bf16(pf1, vf1[nt], oacc[nt], 0, 0, 0);
    }
  }

  // deferred l reduction across the 16 lanes of the quad-row group
#pragma unroll
  for (int o = 1; o < 16; o <<= 1)
#pragma unroll
    for (int r = 0; r < 4; ++r) lsum[r] += __shfl_xor(lsum[r], o, 16);
  float rl[4];
#pragma unroll
  for (int r = 0; r < 4; ++r) rl[r] = 1.0f / lsum[r];   // row 1023: fixed by vmean
#pragma unroll
  for (int nt = 0; nt < 4; ++nt)
#pragma unroll
    for (int r = 0; r < 4; ++r) {
      const int row = u * 16 + quad * 4 + r;
      O[(size_t)(b * SEQ + row) * D_MODEL + h * DKH + nt * 16 + l15] = f2b(oacc[nt][r] * rl[r]);
    }
}

// ---------- row S-1 fixup: fully-masked row => uniform mean over ALL keys ----------
__global__ __launch_bounds__(256) void vmean_kernel(
    const u16* __restrict__ Vt, u16* __restrict__ O)
{
  const int bh = blockIdx.x, tid = threadIdx.x;
  const int d = tid >> 2, sc = (tid & 3) * 256;
  const u16* p = Vt + ((size_t)bh * 64 + d) * SEQ + sc;
  float s = 0.f;
#pragma unroll 8
  for (int i = 0; i < 256; ++i) s += b2f(p[i]);
  s += __shfl_xor(s, 1, 64);
  s += __shfl_xor(s, 2, 64);
  if ((tid & 3) == 0) {
    const int b = bh >> 3, h = bh & 7;
    O[((size_t)b * SEQ + SEQ - 1) * D_MODEL + h * 64 + d] = f2b(s * (1.f / SEQ));
  }
}

// ---------- fused residual add + LayerNorm; T input bf16; writes f32 + bf16 ----------
__global__ __launch_bounds__(256) void add_ln_kernel(
    const float* __restrict__ Hin, const u16* __restrict__ T,
    const float* __restrict__ g, const float* __restrict__ bta,
    float* __restrict__ Hout, u16* __restrict__ Hb)
{
  __shared__ float red[8];
  const int row = blockIdx.x, tid = threadIdx.x;
  const int wave = tid >> 6, lane = tid & 63;
  const size_t base = (size_t)row * D_MODEL;
  const float x0 = Hin[base + tid] + b2f(T[base + tid]);
  const float x1 = Hin[base + tid + 256] + b2f(T[base + tid + 256]);
  float s = x0 + x1;
#pragma unroll
  for (int o = 32; o > 0; o >>= 1) s += __shfl_xor(s, o, 64);
  if (lane == 0) red[wave] = s;
  __syncthreads();
  const float mu = (red[0] + red[1] + red[2] + red[3]) * (1.f / 512.f);
  const float d0 = x0 - mu, d1 = x1 - mu;
  float v = d0 * d0 + d1 * d1;
#pragma unroll
  for (int o = 32; o > 0; o >>= 1) v += __shfl_xor(v, o, 64);
  if (lane == 0) red[4 + wave] = v;
  __syncthreads();
  const float var = (red[4] + red[5] + red[6] + red[7]) * (1.f / 512.f);
  const float rs = rsqrtf(var + 1e-5f);
  const float y0 = d0 * rs * g[tid] + bta[tid];
  const float y1 = d1 * rs * g[tid + 256] + bta[tid + 256];
  Hout[base + tid] = y0;
  Hout[base + tid + 256] = y1;
  Hb[base + tid] = f2b(y0);
  Hb[base + tid + 256] = f2b(y1);
}

extern "C" void kernel_launch(void* const* d_in, const int* in_sizes, int n_in,
                              void* d_out, int out_size, void* d_ws, size_t ws_size,
                              hipStream_t stream) {
  (void)in_sizes; (void)n_in; (void)out_size; (void)ws_size;
  const int*   ids  = (const int*)  d_in[0];
  const float* emb  = (const float*)d_in[1];
  const float* pe   = (const float*)d_in[2];
  const float* Wq   = (const float*)d_in[3];
  const float* bq   = (const float*)d_in[4];
  const float* Wk   = (const float*)d_in[5];
  const float* bk   = (const float*)d_in[6];
  const float* Wv   = (const float*)d_in[7];
  const float* bv   = (const float*)d_in[8];
  const float* Wo   = (const float*)d_in[9];
  const float* bo   = (const float*)d_in[10];
  const float* g1   = (const float*)d_in[11];
  const float* be1  = (const float*)d_in[12];
  const float* W1   = (const float*)d_in[13];
  const float* b1   = (const float*)d_in[14];
  const float* W2   = (const float*)d_in[15];
  const float* b2   = (const float*)d_in[16];
  const float* g2   = (const float*)d_in[17];
  const float* be2  = (const float*)d_in[18];
  const float* Wout = (const float*)d_in[19];
  const float* bout = (const float*)d_in[20];
  float* out = (float*)d_out;

  char* wsp = (char*)d_ws;
  auto alloc = [&](size_t bytes) -> char* {
    char* p = wsp; wsp += (bytes + 255) & ~(size_t)255; return p;
  };
  const size_t dd  = (size_t)D_MODEL * D_MODEL;      // 262144
  const size_t df  = (size_t)D_MODEL * FFN;          // 1048576
  const size_t dq  = (size_t)QKV_LD * D_MODEL;       // 786432
  u16* wqkv_t = (u16*)alloc(NLAYER * dq * 2);
  u16* wo_t   = (u16*)alloc(NLAYER * dd * 2);
  u16* w1_t   = (u16*)alloc(NLAYER * df * 2);
  u16* w2_t   = (u16*)alloc(NLAYER * df * 2);
  u16* wout_t = (u16*)alloc(dd * 2);
  float* bqkv = (float*)alloc(NLAYER * QKV_LD * 4);
  float* hf   = (float*)alloc((size_t)MROWS * D_MODEL * 4);
  u16*   hb   = (u16*)  alloc((size_t)MROWS * D_MODEL * 2);
  u16*   qkvb = (u16*)  alloc((size_t)MROWS * QKV_LD * 2);   // 24 MB
  u16*   ob   = (u16*)  alloc((size_t)MROWS * D_MODEL * 2);  // 8 MB (contiguous after qkvb)
  u16*   vt   = (u16*)  alloc((size_t)BATCH * NHEAD * DKH * SEQ * 2);
  u16*   tb   = (u16*)  alloc((size_t)MROWS * D_MODEL * 2);  // bf16 transform buffer
  u16*   mid  = qkvb;  // FFN mid [8192,2048] aliases qkvb+ob (dead by FFN1; stream-ordered)

  dim3 tb8(32, 8);
  transpose_cvt_kernel<<<dim3(16, 16, NLAYER), tb8, 0, stream>>>(Wq, wqkv_t,            512, 512,  dq, SCALE_LOG2E);
  transpose_cvt_kernel<<<dim3(16, 16, NLAYER), tb8, 0, stream>>>(Wk, wqkv_t + 512*512,  512, 512,  dq, 1.f);
  transpose_cvt_kernel<<<dim3(16, 16, NLAYER), tb8, 0, stream>>>(Wv, wqkv_t + 1024*512, 512, 512,  dq, 1.f);
  transpose_cvt_kernel<<<dim3(16, 16, NLAYER), tb8, 0, stream>>>(Wo, wo_t,   512, 512,  dd, 1.f);
  transpose_cvt_kernel<<<dim3(64, 16, NLAYER), tb8, 0, stream>>>(W1, w1_t,   512, 2048, df, 1.f);
  transpose_cvt_kernel<<<dim3(16, 64, NLAYER), tb8, 0, stream>>>(W2, w2_t,   2048, 512, df, 1.f);
  transpose_cvt_kernel<<<dim3(16, 16, 1),      tb8, 0, stream>>>(Wout, wout_t, 512, 512, dd, 1.f);
  concat_bias_kernel<<<NLAYER, 256, 0, stream>>>(bq, bk, bv, bqkv);

  embed_kernel<<<MROWS, 256, 0, stream>>>(ids, emb, pe, hf, hb);

  for (int l = 0; l < NLAYER; ++l) {
    gemm_kernel<128, false, false, true, true><<<dim3(64, 12), 256, 0, stream>>>(
        hb, wqkv_t + l * dq, bqkv + l * QKV_LD, nullptr, qkvb, vt, MROWS, QKV_LD, 512);
    attn_mfma_kernel<<<1024, 256, 0, stream>>>(qkvb, vt, ob);
    vmean_kernel<<<64, 256, 0, stream>>>(vt, ob);
    gemm_kernel<64, false, false, true, false><<<dim3(128, 4), 256, 0, stream>>>(
        ob, wo_t + l * dd, bo + l * 512, nullptr, tb, nullptr, MROWS, 512, 512);
    add_ln_kernel<<<MROWS, 256, 0, stream>>>(hf, tb, g1 + l * 512, be1 + l * 512, hf, hb);
    gemm_kernel<128, true, false, true, false><<<dim3(64, 16), 256, 0, stream>>>(
        hb, w1_t + l * df, b1 + l * 2048, nullptr, mid, nullptr, MROWS, 2048, 512);
    gemm_kernel<64, false, false, true, false><<<dim3(128, 4), 256, 0, stream>>>(
        mid, w2_t + l * df, b2 + l * 512, nullptr, tb, nullptr, MROWS, 512, 2048);
    add_ln_kernel<<<MROWS, 256, 0, stream>>>(hf, tb, g2 + l * 512, be2 + l * 512, hf, hb);
  }
  gemm_kernel<64, false, true, false, false><<<dim3(128, 4), 256, 0, stream>>>(
      hb, wout_t, bout, out, nullptr, nullptr, MROWS, 512, 512);
}

// Round 7
// 1137.862 us; speedup vs baseline: 1.2738x; 1.2387x over previous
//
#include <hip/hip_runtime.h>

typedef unsigned short u16;
typedef __attribute__((ext_vector_type(8))) short bf16x8;   // 8 bf16 (4 VGPRs)
typedef __attribute__((ext_vector_type(4))) float f32x4;
typedef __attribute__((ext_vector_type(4))) unsigned int uint4v;
typedef __attribute__((ext_vector_type(4))) unsigned short us4;

#define NLAYER 6
#define D_MODEL 512
#define NHEAD 8
#define DKH 64
#define SEQ 1024
#define BATCH 8
#define FFN 2048
#define MROWS (BATCH * SEQ)  /* 8192 */
#define QKV_LD 1536
#define SCALE_LOG2E 0.18033688011112042f  /* (1/sqrt(64)) * log2(e), folded into Wq/bq */

__device__ __forceinline__ float b2f(u16 u) {
  union { unsigned u32; float f; } x; x.u32 = ((unsigned)u) << 16; return x.f;
}
__device__ __forceinline__ u16 f2b(float f) {
  union { float f; unsigned u; } x; x.f = f;
  unsigned r = x.u + 0x7FFFu + ((x.u >> 16) & 1u);   // RNE
  return (u16)(r >> 16);
}
// async global->LDS, 16B per lane; LDS dest = wave-uniform base + lane*16 (m97)
__device__ __forceinline__ void gld16(const u16* g, u16* l) {
  __builtin_amdgcn_global_load_lds(
      (const __attribute__((address_space(1))) unsigned int*)g,
      (__attribute__((address_space(3))) unsigned int*)l, 16, 0, 0);
}

// ---------- weight transpose + f32->bf16 (scale folds attn score scale into Wq) ----------
__global__ __launch_bounds__(256) void transpose_cvt_kernel(
    const float* __restrict__ src, u16* __restrict__ dst, int K, int N, size_t dstZ,
    float scale)
{
  __shared__ float t[32][33];
  const int z = blockIdx.z;
  src += (size_t)z * K * N;
  dst += (size_t)z * dstZ;
  const int n0 = blockIdx.x * 32, k0 = blockIdx.y * 32;
  const int tx = threadIdx.x, ty = threadIdx.y;  // 32 x 8
#pragma unroll
  for (int i = 0; i < 32; i += 8)
    t[ty + i][tx] = src[(size_t)(k0 + ty + i) * N + n0 + tx];
  __syncthreads();
#pragma unroll
  for (int i = 0; i < 32; i += 8)
    dst[(size_t)(n0 + ty + i) * K + k0 + tx] = f2b(t[tx][ty + i] * scale);
}

// ---------- concat per-layer q/k/v biases into [L][1536]; bq pre-scaled ----------
__global__ __launch_bounds__(256) void concat_bias_kernel(
    const float* __restrict__ bq, const float* __restrict__ bk,
    const float* __restrict__ bv, float* __restrict__ dst)
{
  const int l = blockIdx.x, t = threadIdx.x;
#pragma unroll
  for (int j = t; j < 512; j += 256) {
    dst[l * QKV_LD + j]        = bq[l * 512 + j] * SCALE_LOG2E;
    dst[l * QKV_LD + 512 + j]  = bk[l * 512 + j];
    dst[l * QKV_LD + 1024 + j] = bv[l * 512 + j];
  }
}

// ---------- embedding: h = emb[ids]*sqrt(D) + pe[s] ----------
__global__ __launch_bounds__(256) void embed_kernel(
    const int* __restrict__ ids, const float* __restrict__ emb,
    const float* __restrict__ pe, float* __restrict__ Hf, u16* __restrict__ Hb)
{
  const int row = blockIdx.x;
  const int s = row & (SEQ - 1);
  const int id = ids[row];
  const int tid = threadIdx.x;
#pragma unroll
  for (int u = 0; u < 2; ++u) {
    const int d = tid + u * 256;
    float v = emb[(size_t)id * D_MODEL + d] * 22.62741699796952f + pe[(size_t)s * D_MODEL + d];
    Hf[(size_t)row * D_MODEL + d] = v;
    Hb[(size_t)row * D_MODEL + d] = f2b(v);
  }
}

// ---------- bf16 MFMA GEMM: C[M,N] = A[M,K] @ Bt[N,K]^T + bias ----------
// BMTx128 tile, BK=32, global_load_lds(16B) staging (m97 pattern).
// VT mode (QKV GEMM): columns n>=1024 (the V projection) are written
// TRANSPOSED into Vt[bh][d][s] as packed 4x bf16 (8B) stores.
template<int BMT, bool RELU, bool OUTF, bool OUTB, bool VT>
__global__ __launch_bounds__(256) void gemm_kernel(
    const u16* __restrict__ A, const u16* __restrict__ Bt,
    const float* __restrict__ bias,
    float* __restrict__ Cf, u16* __restrict__ Cb, u16* __restrict__ Vtp,
    int M, int N, int K)
{
  constexpr int IT = BMT / 32;                      // 4 (BMT=128) or 2 (BMT=64)
  __shared__ __align__(16) u16 As[BMT * 32];
  __shared__ __align__(16) u16 Bs[128 * 32];
  const int tid = threadIdx.x;
  const int bm = blockIdx.x * BMT, bn = blockIdx.y * 128;
  const int wave = tid >> 6, lane = tid & 63;
  const int lm = lane & 15, quad = lane >> 4;
  const int wm = (wave & 1) * (BMT / 2), wn = (wave >> 1) * 64;
  const int r0 = tid >> 2;            // 0..63
  const int c0 = (tid & 3) * 8;       // 0,8,16,24

  const u16* Ap = A  + (size_t)(bm + r0) * K + c0;
  const u16* Bp = Bt + (size_t)(bn + r0) * K + c0;
  // LDS layout: byte offset == tid*16 for chunk 0 (lane-linear, required by gld)
  u16* lA  = As + wave * 512;
  u16* lA2 = lA + 64 * 32;
  u16* lB  = Bs + wave * 512;
  u16* lB2 = lB + 64 * 32;

  f32x4 acc[IT][4] = {};

  for (int kk = 0; kk < K; kk += 32) {
    __syncthreads();                  // prior iter's frag reads done
    gld16(Ap + kk, lA);
    if (BMT == 128) gld16(Ap + kk + (size_t)64 * K, lA2);
    gld16(Bp + kk, lB);
    gld16(Bp + kk + (size_t)64 * K, lB2);
    __syncthreads();                  // compiler emits vmcnt(0) drain before barrier
    bf16x8 af[IT], bg[4];
#pragma unroll
    for (int i = 0; i < IT; ++i)
      af[i] = *(const bf16x8*)&As[(wm + i * 16 + lm) * 32 + quad * 8];
#pragma unroll
    for (int j = 0; j < 4; ++j)
      bg[j] = *(const bf16x8*)&Bs[(wn + j * 16 + lm) * 32 + quad * 8];
#pragma unroll
    for (int i = 0; i < IT; ++i)
#pragma unroll
      for (int j = 0; j < 4; ++j)
        acc[i][j] = __builtin_amdgcn_mfma_f32_16x16x32_bf16(af[i], bg[j], acc[i][j], 0, 0, 0);
  }

  // epilogue: D row = quad*4+reg, col = lm
  const int mbase = bm + wm + quad * 4;
  const int nbase = bn + wn + lm;
#pragma unroll
  for (int i = 0; i < IT; ++i) {
#pragma unroll
    for (int j = 0; j < 4; ++j) {
      const int n = nbase + j * 16;
      const float bv = bias[n];
      float vv[4];
#pragma unroll
      for (int r = 0; r < 4; ++r) {
        float v = acc[i][j][r] + bv;
        if (RELU) v = fmaxf(v, 0.f);
        vv[r] = v;
      }
      if (VT && n >= 1024) {
        // V column: write transposed, 4 consecutive s per lane (8B store)
        const int hh = (n - 1024) >> 6, d = (n - 1024) & 63;
        const int mm = mbase + i * 16;               // mm..mm+3, 4-aligned
        const int bb = mm >> 10, ss = mm & 1023;
        us4 pk;
#pragma unroll
        for (int r = 0; r < 4; ++r) pk[r] = f2b(vv[r]);
        *(us4*)&Vtp[(((size_t)(bb * NHEAD + hh)) * 64 + d) * SEQ + ss] = pk;
      } else {
#pragma unroll
        for (int r = 0; r < 4; ++r) {
          const int m = mbase + i * 16 + r;
          if (OUTF) Cf[(size_t)m * N + n] = vv[r];
          if (OUTB) Cb[(size_t)m * N + n] = f2b(vv[r]);
        }
      }
    }
  }
}

// ---------- MFMA flash attention, LDS-shared K/V tiles, anti-causal mask (j > i) ----------
// Block = 4 waves, wave w owns q-unit u = 4*(id>>6)+w -> jt0 = id>>6 is
// block-uniform: all waves iterate the SAME tile range in lockstep.
// K/V tile staged ONCE per block per step (256 lines vs 1024 for per-wave
// register loads - the TA line-request pipe was the R3-R6 bottleneck).
// XOR-swizzled LDS (measured 0 conflicts); register prefetch of tile jt+1;
// max-free exp2 softmax (scale folded into Wq/bq).
// 1-D grid: id&63 = bh, so all 16 blocks of a (b,h) share id%8 -> same XCD.
__global__ __launch_bounds__(256) void attn_mfma_kernel(
    const u16* __restrict__ QKV, const u16* __restrict__ Vt, u16* __restrict__ O)
{
  __shared__ __align__(16) u16 Ks[64 * 64];
  __shared__ __align__(16) u16 Vs[64 * 64];
  __shared__ __align__(16) u16 Ps[4 * 16 * 64];
  const int tid = threadIdx.x;
  const int wave = tid >> 6, lane = tid & 63;
  const int quad = lane >> 4, l15 = lane & 15;
  const int l7 = l15 & 7;
  const int id = blockIdx.x;
  const int bh = id & 63;                           // id%8 == h -> XCD affinity
  const int b = bh >> 3, h = bh & 7;
  const int g = id >> 6;                            // 0..15 == jt0 (block-uniform)
  const int u = g * 4 + wave;                       // q-unit 0..63
  u16* psw = Ps + wave * (16 * 64);
  const size_t qoff = (size_t)b * SEQ * QKV_LD + h * 64;
  const size_t vtb  = (size_t)bh * 64 * SEQ;

  // staging coords: row sr = tid>>3 (0..31, +32 second half), chunk sc = tid&7
  const int sr = tid >> 3, sc = tid & 7;
  const u16* kg0 = QKV + qoff + 512 + (size_t)sr * QKV_LD + sc * 8;
  const u16* kg1 = kg0 + (size_t)32 * QKV_LD;
  const u16* vg0 = Vt + vtb + (size_t)sr * SEQ + sc * 8;
  const u16* vg1 = vg0 + (size_t)32 * SEQ;
  const int sw = (sc ^ (sr & 7)) << 3;              // (sr+32)&7 == sr&7
  u16* ks0 = &Ks[sr * 64 + sw];
  u16* ks1 = &Ks[(sr + 32) * 64 + sw];
  u16* vs0 = &Vs[sr * 64 + sw];
  u16* vs1 = &Vs[(sr + 32) * 64 + sw];

  const u16* qp = QKV + qoff + (size_t)(u * 16 + l15) * QKV_LD + quad * 8;
  const bf16x8 qf0 = *(const bf16x8*)(qp);
  const bf16x8 qf1 = *(const bf16x8*)(qp + 32);

  f32x4 oacc[4] = {};
  float lsum[4] = {0.f, 0.f, 0.f, 0.f};

  // prologue: load tile g into registers
  uint4v kr0 = *(const uint4v*)(kg0 + (size_t)(g * 64) * QKV_LD);
  uint4v kr1 = *(const uint4v*)(kg1 + (size_t)(g * 64) * QKV_LD);
  uint4v vr0 = *(const uint4v*)(vg0 + g * 64);
  uint4v vr1 = *(const uint4v*)(vg1 + g * 64);

#pragma unroll 1
  for (int jt = g; jt < 16; ++jt) {
    __syncthreads();                  // prior iter's frag reads done
    *(uint4v*)ks0 = kr0; *(uint4v*)ks1 = kr1;
    *(uint4v*)vs0 = vr0; *(uint4v*)vs1 = vr1;
    __syncthreads();
    if (jt < 15) {                    // register prefetch of next tile (m93 pattern)
      kr0 = *(const uint4v*)(kg0 + (size_t)((jt + 1) * 64) * QKV_LD);
      kr1 = *(const uint4v*)(kg1 + (size_t)((jt + 1) * 64) * QKV_LD);
      vr0 = *(const uint4v*)(vg0 + (jt + 1) * 64);
      vr1 = *(const uint4v*)(vg1 + (jt + 1) * 64);
    }
    // QK from LDS
    f32x4 sacc[4] = {};
#pragma unroll
    for (int nt = 0; nt < 4; ++nt) {
      const int key = nt * 16 + l15, k7 = key & 7;
      bf16x8 kb0 = *(const bf16x8*)&Ks[key * 64 + ((quad ^ k7) << 3)];
      bf16x8 kb1 = *(const bf16x8*)&Ks[key * 64 + (((quad + 4) ^ k7) << 3)];
      sacc[nt] = __builtin_amdgcn_mfma_f32_16x16x32_bf16(qf0, kb0, sacc[nt], 0, 0, 0);
      sacc[nt] = __builtin_amdgcn_mfma_f32_16x16x32_bf16(qf1, kb1, sacc[nt], 0, 0, 0);
    }
    // max-free softmax (scale pre-folded into Q): p = exp2(s), mask on diag tile
    const bool diag = (jt == g);
#pragma unroll
    for (int nt = 0; nt < 4; ++nt)
#pragma unroll
      for (int r = 0; r < 4; ++r) {
        float pv = __builtin_amdgcn_exp2f(sacc[nt][r]);
        if (diag) {
          const int i = u * 16 + quad * 4 + r;
          const int j = jt * 64 + nt * 16 + l15;
          pv = (j > i) ? pv : 0.f;                  // keep strictly j > i
        }
        lsum[r] += pv;
        const int qr = quad * 4 + r;
        const int j2 = nt * 16 + l15;
        psw[qr * 64 + (((j2 >> 3) ^ (qr & 7)) << 3) + (j2 & 7)] = f2b(pv);
      }
    // P frags from per-wave LDS (same-wave RAW, no barrier)
    bf16x8 pf0 = *(const bf16x8*)&psw[l15 * 64 + (((quad + 0) ^ l7) << 3)];
    bf16x8 pf1 = *(const bf16x8*)&psw[l15 * 64 + (((quad + 4) ^ l7) << 3)];
    // PV from LDS
#pragma unroll
    for (int nt = 0; nt < 4; ++nt) {
      const int d = nt * 16 + l15, d7 = d & 7;
      bf16x8 vb0 = *(const bf16x8*)&Vs[d * 64 + ((quad ^ d7) << 3)];
      bf16x8 vb1 = *(const bf16x8*)&Vs[d * 64 + (((quad + 4) ^ d7) << 3)];
      oacc[nt] = __builtin_amdgcn_mfma_f32_16x16x32_bf16(pf0, vb0, oacc[nt], 0, 0, 0);
      oacc[nt] = __builtin_amdgcn_mfma_f32_16x16x32_bf16(pf1, vb1, oacc[nt], 0, 0, 0);
    }
  }

  // deferred l reduction across the 16 lanes of the quad-row group
#pragma unroll
  for (int o = 1; o < 16; o <<= 1)
#pragma unroll
    for (int r = 0; r < 4; ++r) lsum[r] += __shfl_xor(lsum[r], o, 16);
  float rl[4];
#pragma unroll
  for (int r = 0; r < 4; ++r) rl[r] = 1.0f / lsum[r];   // row 1023: fixed by vmean
#pragma unroll
  for (int nt = 0; nt < 4; ++nt)
#pragma unroll
    for (int r = 0; r < 4; ++r) {
      const int row = u * 16 + quad * 4 + r;
      O[(size_t)(b * SEQ + row) * D_MODEL + h * DKH + nt * 16 + l15] = f2b(oacc[nt][r] * rl[r]);
    }
}

// ---------- row S-1 fixup: fully-masked row => uniform mean over ALL keys ----------
__global__ __launch_bounds__(256) void vmean_kernel(
    const u16* __restrict__ Vt, u16* __restrict__ O)
{
  const int bh = blockIdx.x, tid = threadIdx.x;
  const int d = tid >> 2, sc = (tid & 3) * 256;
  const u16* p = Vt + ((size_t)bh * 64 + d) * SEQ + sc;
  float s = 0.f;
#pragma unroll 8
  for (int i = 0; i < 256; ++i) s += b2f(p[i]);
  s += __shfl_xor(s, 1, 64);
  s += __shfl_xor(s, 2, 64);
  if ((tid & 3) == 0) {
    const int b = bh >> 3, h = bh & 7;
    O[((size_t)b * SEQ + SEQ - 1) * D_MODEL + h * 64 + d] = f2b(s * (1.f / SEQ));
  }
}

// ---------- fused residual add + LayerNorm; T input bf16; writes f32 + bf16 ----------
__global__ __launch_bounds__(256) void add_ln_kernel(
    const float* __restrict__ Hin, const u16* __restrict__ T,
    const float* __restrict__ g, const float* __restrict__ bta,
    float* __restrict__ Hout, u16* __restrict__ Hb)
{
  __shared__ float red[8];
  const int row = blockIdx.x, tid = threadIdx.x;
  const int wave = tid >> 6, lane = tid & 63;
  const size_t base = (size_t)row * D_MODEL;
  const float x0 = Hin[base + tid] + b2f(T[base + tid]);
  const float x1 = Hin[base + tid + 256] + b2f(T[base + tid + 256]);
  float s = x0 + x1;
#pragma unroll
  for (int o = 32; o > 0; o >>= 1) s += __shfl_xor(s, o, 64);
  if (lane == 0) red[wave] = s;
  __syncthreads();
  const float mu = (red[0] + red[1] + red[2] + red[3]) * (1.f / 512.f);
  const float d0 = x0 - mu, d1 = x1 - mu;
  float v = d0 * d0 + d1 * d1;
#pragma unroll
  for (int o = 32; o > 0; o >>= 1) v += __shfl_xor(v, o, 64);
  if (lane == 0) red[4 + wave] = v;
  __syncthreads();
  const float var = (red[4] + red[5] + red[6] + red[7]) * (1.f / 512.f);
  const float rs = rsqrtf(var + 1e-5f);
  const float y0 = d0 * rs * g[tid] + bta[tid];
  const float y1 = d1 * rs * g[tid + 256] + bta[tid + 256];
  Hout[base + tid] = y0;
  Hout[base + tid + 256] = y1;
  Hb[base + tid] = f2b(y0);
  Hb[base + tid + 256] = f2b(y1);
}

extern "C" void kernel_launch(void* const* d_in, const int* in_sizes, int n_in,
                              void* d_out, int out_size, void* d_ws, size_t ws_size,
                              hipStream_t stream) {
  (void)in_sizes; (void)n_in; (void)out_size; (void)ws_size;
  const int*   ids  = (const int*)  d_in[0];
  const float* emb  = (const float*)d_in[1];
  const float* pe   = (const float*)d_in[2];
  const float* Wq   = (const float*)d_in[3];
  const float* bq   = (const float*)d_in[4];
  const float* Wk   = (const float*)d_in[5];
  const float* bk   = (const float*)d_in[6];
  const float* Wv   = (const float*)d_in[7];
  const float* bv   = (const float*)d_in[8];
  const float* Wo   = (const float*)d_in[9];
  const float* bo   = (const float*)d_in[10];
  const float* g1   = (const float*)d_in[11];
  const float* be1  = (const float*)d_in[12];
  const float* W1   = (const float*)d_in[13];
  const float* b1   = (const float*)d_in[14];
  const float* W2   = (const float*)d_in[15];
  const float* b2   = (const float*)d_in[16];
  const float* g2   = (const float*)d_in[17];
  const float* be2  = (const float*)d_in[18];
  const float* Wout = (const float*)d_in[19];
  const float* bout = (const float*)d_in[20];
  float* out = (float*)d_out;

  char* wsp = (char*)d_ws;
  auto alloc = [&](size_t bytes) -> char* {
    char* p = wsp; wsp += (bytes + 255) & ~(size_t)255; return p;
  };
  const size_t dd  = (size_t)D_MODEL * D_MODEL;      // 262144
  const size_t df  = (size_t)D_MODEL * FFN;          // 1048576
  const size_t dq  = (size_t)QKV_LD * D_MODEL;       // 786432
  u16* wqkv_t = (u16*)alloc(NLAYER * dq * 2);
  u16* wo_t   = (u16*)alloc(NLAYER * dd * 2);
  u16* w1_t   = (u16*)alloc(NLAYER * df * 2);
  u16* w2_t   = (u16*)alloc(NLAYER * df * 2);
  u16* wout_t = (u16*)alloc(dd * 2);
  float* bqkv = (float*)alloc(NLAYER * QKV_LD * 4);
  float* hf   = (float*)alloc((size_t)MROWS * D_MODEL * 4);
  u16*   hb   = (u16*)  alloc((size_t)MROWS * D_MODEL * 2);
  u16*   qkvb = (u16*)  alloc((size_t)MROWS * QKV_LD * 2);   // 24 MB
  u16*   ob   = (u16*)  alloc((size_t)MROWS * D_MODEL * 2);  // 8 MB (contiguous after qkvb)
  u16*   vt   = (u16*)  alloc((size_t)BATCH * NHEAD * DKH * SEQ * 2);
  u16*   tb   = (u16*)  alloc((size_t)MROWS * D_MODEL * 2);  // bf16 transform buffer
  u16*   mid  = qkvb;  // FFN mid [8192,2048] aliases qkvb+ob (dead by FFN1; stream-ordered)

  dim3 tb8(32, 8);
  transpose_cvt_kernel<<<dim3(16, 16, NLAYER), tb8, 0, stream>>>(Wq, wqkv_t,            512, 512,  dq, SCALE_LOG2E);
  transpose_cvt_kernel<<<dim3(16, 16, NLAYER), tb8, 0, stream>>>(Wk, wqkv_t + 512*512,  512, 512,  dq, 1.f);
  transpose_cvt_kernel<<<dim3(16, 16, NLAYER), tb8, 0, stream>>>(Wv, wqkv_t + 1024*512, 512, 512,  dq, 1.f);
  transpose_cvt_kernel<<<dim3(16, 16, NLAYER), tb8, 0, stream>>>(Wo, wo_t,   512, 512,  dd, 1.f);
  transpose_cvt_kernel<<<dim3(64, 16, NLAYER), tb8, 0, stream>>>(W1, w1_t,   512, 2048, df, 1.f);
  transpose_cvt_kernel<<<dim3(16, 64, NLAYER), tb8, 0, stream>>>(W2, w2_t,   2048, 512, df, 1.f);
  transpose_cvt_kernel<<<dim3(16, 16, 1),      tb8, 0, stream>>>(Wout, wout_t, 512, 512, dd, 1.f);
  concat_bias_kernel<<<NLAYER, 256, 0, stream>>>(bq, bk, bv, bqkv);

  embed_kernel<<<MROWS, 256, 0, stream>>>(ids, emb, pe, hf, hb);

  for (int l = 0; l < NLAYER; ++l) {
    gemm_kernel<128, false, false, true, true><<<dim3(64, 12), 256, 0, stream>>>(
        hb, wqkv_t + l * dq, bqkv + l * QKV_LD, nullptr, qkvb, vt, MROWS, QKV_LD, 512);
    attn_mfma_kernel<<<1024, 256, 0, stream>>>(qkvb, vt, ob);
    vmean_kernel<<<64, 256, 0, stream>>>(vt, ob);
    gemm_kernel<64, false, false, true, false><<<dim3(128, 4), 256, 0, stream>>>(
        ob, wo_t + l * dd, bo + l * 512, nullptr, tb, nullptr, MROWS, 512, 512);
    add_ln_kernel<<<MROWS, 256, 0, stream>>>(hf, tb, g1 + l * 512, be1 + l * 512, hf, hb);
    gemm_kernel<128, true, false, true, false><<<dim3(64, 16), 256, 0, stream>>>(
        hb, w1_t + l * df, b1 + l * 2048, nullptr, mid, nullptr, MROWS, 2048, 512);
    gemm_kernel<64, false, false, true, false><<<dim3(128, 4), 256, 0, stream>>>(
        mid, w2_t + l * df, b2 + l * 512, nullptr, tb, nullptr, MROWS, 512, 2048);
    add_ln_kernel<<<MROWS, 256, 0, stream>>>(hf, tb, g2 + l * 512, be2 + l * 512, hf, hb);
  }
  gemm_kernel<64, false, true, false, false><<<dim3(128, 4), 256, 0, stream>>>(
      hb, wout_t, bout, out, nullptr, nullptr, MROWS, 512, 512);
}